// Round 10
// baseline (207.100 us; speedup 1.0000x reference)
//
#include <hip/hip_runtime.h>
#include <hip/hip_bf16.h>

#define BB 8
#define CC 256
#define NN 4096
#define LOG2E 1.44269504088896340736f
#define SHIFT 48.0f

typedef __attribute__((ext_vector_type(8))) short short8;
typedef __attribute__((ext_vector_type(4))) float f32x4;
typedef __attribute__((ext_vector_type(16))) float f32x16;

static __device__ __forceinline__ unsigned short f2b(float x) {
  __hip_bfloat16 h = __float2bfloat16(x);   // RNE
  return *reinterpret_cast<unsigned short*>(&h);
}
static __device__ __forceinline__ unsigned int pk2(float a, float b) {
  return (unsigned int)f2b(a) | ((unsigned int)f2b(b) << 16);
}

// ---------------------------------------------------------------------------
// ws layout (bytes):
//   cshift @ 131072 : [B][N] f32  c[k] = SHIFT + log2(sum exp2(S-SHIFT))
//   wA   @ 262144   : [20 mg][8 kg][64 l][8 e] bf16 W A-frags    163840
//   ball @ 425984   : [320] f32 biases (f rows pre-scaled LOG2E)   1280
//   fA   @ 427520   : [B][256 kg][64 l][8 e] bf16 (f^T*LOG2E)   2097152
//   gB   @ 2524672  : [B][256 ig][64 l][8 e] bf16               2097152
//   hA   @ 4621824  : [B][8 cg][256 kc][64 l][8 e] bf16        16777216
//                     (32x32x16 B-frags: c=cg*32+(l&31), k=kc*16+(l>>5)*8+e)
// 16x16x32 frags (m89/m91-verified):
//   A[m][k]: lane l holds m=l&15, k=(l>>4)*8+e   (B[k][n] identical bits)
//   D[m][n]: lane l reg r holds m=(l>>4)*4+r, n=l&15
// 32x32x16 frags (C/D verified m74/m101; A/B standard-CDNA extension):
//   A[m][k]: lane l holds m=l&31, k=(l>>5)*8+e   (B[k][n] identical bits)
//   D[m][n]: lane l reg r: n=l&31, m=(r&3)+8*(r>>2)+4*(l>>5)
// P = exp2(S - c[k]) with c >= rowmax  ->  P in [0,1], no inf/NaN possible.
// k_out (round 10): PV on 32x32x16 (2x arithmetic intensity), 4-wave blocks,
// tile i128 x c128, 64x64 wave tiles (2x2 reuse), grid 512 = 2 blocks/CU.
// ---------------------------------------------------------------------------

// Kernel 0: W -> A-frags (bf16), LOG2E folded into f rows; biases -> ball.
__global__ __launch_bounds__(256) void k_wprep(
    const float* __restrict__ Wf, const float* __restrict__ bfv,
    const float* __restrict__ Wg, const float* __restrict__ bgv,
    const float* __restrict__ Wh, const float* __restrict__ bhv,
    unsigned short* __restrict__ wA, float* __restrict__ ball)
{
  const int t = threadIdx.x;
  const int fi = blockIdx.x * 4 + (t >> 6);   // frag index 0..159 (mg*8+kg)
  const int l = t & 63;
  const int mg = fi >> 3, kg = fi & 7;
  const int o = mg * 16 + (l & 15);
  const int c0 = kg * 32 + (l >> 4) * 8;
  const float* src; float scale = 1.0f;
  if (o < 32)      { src = Wf + (size_t)o * CC; scale = LOG2E; }
  else if (o < 64) { src = Wg + (size_t)(o - 32) * CC; }
  else             { src = Wh + (size_t)(o - 64) * CC; }
  float4 a = *(const float4*)(src + c0);
  float4 c = *(const float4*)(src + c0 + 4);
  short8 v;
  v[0] = (short)f2b(a.x * scale); v[1] = (short)f2b(a.y * scale);
  v[2] = (short)f2b(a.z * scale); v[3] = (short)f2b(a.w * scale);
  v[4] = (short)f2b(c.x * scale); v[5] = (short)f2b(c.y * scale);
  v[6] = (short)f2b(c.z * scale); v[7] = (short)f2b(c.w * scale);
  *(short8*)(wA + (size_t)fi * 512 + l * 8) = v;
  if (blockIdx.x == 0 && t < 320)
    ball[t] = (t < 32) ? bfv[t] * LOG2E : (t < 64) ? bgv[t - 32] : bhv[t - 64];
}

// Kernel 1: fused projection GEMM (bf16 MFMA) -> frag-ready fA/gB/hA.
__global__ __launch_bounds__(512) void k_fgh(
    const float* __restrict__ x, const unsigned short* __restrict__ wA,
    const float* __restrict__ ball,
    unsigned short* __restrict__ fA, unsigned short* __restrict__ gB,
    unsigned short* __restrict__ hA)
{
  __shared__ __align__(16) char smem[41984];       // max(xb 8KB, TL 41KB)
  unsigned short* xb = (unsigned short*)smem;      // [8 frag][64 l][8 e]
  unsigned short* TL = (unsigned short*)smem;      // [64 i][328 o] bf16
  const int bid = blockIdx.x;
  const int b = bid & 7, i0 = (bid >> 3) * 64;     // batch pinned to XCD
  const int t = threadIdx.x, w = t >> 6, l = t & 63;
  const int ig_w = w & 3, mg0 = (w >> 2) * 10;
  f32x4 acc[10] = {};
  for (int cc = 0; cc < 4; ++cc) {                 // c-chunks of 64
    __syncthreads();
    {  // stage x[cc*64..+64][i0..i0+64] as 8 B-frags (bf16)
      short8 v;
      const float* xp = x + ((size_t)b * CC + cc * 64 + w * 8) * NN + i0 + l;
      #pragma unroll
      for (int e = 0; e < 8; ++e) v[e] = (short)f2b(xp[(size_t)e * NN]);
      int frag = (w >> 2) * 4 + (l >> 4);
      int lp = (w & 3) * 16 + (l & 15);
      *(short8*)(xb + (frag * 64 + lp) * 8) = v;
    }
    __syncthreads();
    #pragma unroll
    for (int kg2 = 0; kg2 < 2; ++kg2) {
      short8 bfrag = *(const short8*)(xb + ((kg2 * 4 + ig_w) * 64 + l) * 8);
      int kg = cc * 2 + kg2;
      #pragma unroll
      for (int j = 0; j < 10; ++j) {
        short8 afrag = *(const short8*)(wA +
            ((size_t)((mg0 + j) * 8 + kg)) * 512 + l * 8);
        acc[j] = __builtin_amdgcn_mfma_f32_16x16x32_bf16(afrag, bfrag, acc[j], 0, 0, 0);
      }
    }
  }
  __syncthreads();
  // D-frags (+bias) -> transpose tile TL[i][o]
  #pragma unroll
  for (int j = 0; j < 10; ++j) {
    int ob = (mg0 + j) * 16 + (l >> 4) * 4;
    float4 bl = *(const float4*)(ball + ob);
    int irow = ig_w * 16 + (l & 15);
    ushort4 pv;
    pv.x = f2b(acc[j][0] + bl.x); pv.y = f2b(acc[j][1] + bl.y);
    pv.z = f2b(acc[j][2] + bl.z); pv.w = f2b(acc[j][3] + bl.w);
    *(ushort4*)(TL + irow * 328 + ob) = pv;
  }
  __syncthreads();
  // pack fA (o 0..31, already LOG2E-scaled) and gB (o 32..63) — 16x16 frags
  if (t < 256) {
    int kg_p = t >> 6;
    int o8 = (l >> 4) * 8;
    int irow = kg_p * 16 + (l & 15);
    short8 vf = *(const short8*)(TL + irow * 328 + o8);
    short8 vg = *(const short8*)(TL + irow * 328 + 32 + o8);
    size_t kgG = (size_t)b * 256 + (i0 >> 4) + kg_p;
    *(short8*)(fA + kgG * 512 + l * 8) = vf;
    *(short8*)(gB + kgG * 512 + l * 8) = vg;
  }
  // pack hA (o 64..319) as 32x32x16 B-frags: 32 frags x 64 lanes / 2048 slots
  #pragma unroll
  for (int q = 0; q < 4; ++q) {
    int slot = t + q * 512;
    int fr = slot >> 6, ll = slot & 63;
    int cg = fr >> 2, kcl = fr & 3;
    int orow = 64 + cg * 32 + (ll & 31);
    int pbase = kcl * 16 + (ll >> 5) * 8;
    short8 v;
    #pragma unroll
    for (int e = 0; e < 8; ++e) v[e] = (short)TL[(pbase + e) * 328 + orow];
    size_t idx = (((size_t)b * 8 + cg) * 256 + (i0 >> 4) + kcl) * 512 + ll * 8;
    *(short8*)(hA + idx) = v;
  }
}

// Kernel 2: fixed-shift softmax denom, LDS-staged g tiles shared by 8 waves.
__global__ __launch_bounds__(512) void k_stats(
    const unsigned short* __restrict__ fA, const unsigned short* __restrict__ gB,
    float* __restrict__ cshift)
{
  __shared__ __align__(16) unsigned short sg[2][16 * 512];   // 2 x 16 KB
  const int bid = blockIdx.x;
  const int b = bid & 7, kt = bid >> 3;
  const int t = threadIdx.x, w = t >> 6, l = t & 63;
  const int li = l & 15, lh = l >> 4;
  short8 af = *(const short8*)(fA + ((size_t)b * 256 + kt * 8 + w) * 512 + l * 8);
  const unsigned short* gb = gB + (size_t)b * 256 * 512;
  f32x4 zero = {0.f, 0.f, 0.f, 0.f};
  {
    uint4 v0 = *(const uint4*)(gb + ((size_t)(w * 2 + 0) * 64 + l) * 8);
    uint4 v1 = *(const uint4*)(gb + ((size_t)(w * 2 + 1) * 64 + l) * 8);
    *(uint4*)(&sg[0][((w * 2 + 0) * 64 + l) * 8]) = v0;
    *(uint4*)(&sg[0][((w * 2 + 1) * 64 + l) * 8]) = v1;
  }
  __syncthreads();
  float s[4] = {0.f, 0.f, 0.f, 0.f};
  for (int jt = 0; jt < 16; ++jt) {
    if (jt < 15) {
      uint4 v0 = *(const uint4*)(gb + ((size_t)((jt + 1) * 16 + w * 2 + 0) * 64 + l) * 8);
      uint4 v1 = *(const uint4*)(gb + ((size_t)((jt + 1) * 16 + w * 2 + 1) * 64 + l) * 8);
      unsigned short* dst = &sg[(jt + 1) & 1][0];
      *(uint4*)(dst + ((w * 2 + 0) * 64 + l) * 8) = v0;
      *(uint4*)(dst + ((w * 2 + 1) * 64 + l) * 8) = v1;
    }
    const unsigned short* src = &sg[jt & 1][0];
    #pragma unroll
    for (int jf = 0; jf < 16; ++jf) {
      short8 bfrag = *(const short8*)(src + (jf * 64 + l) * 8);
      f32x4 d = __builtin_amdgcn_mfma_f32_16x16x32_bf16(af, bfrag, zero, 0, 0, 0);
      s[0] += exp2f(d[0] - SHIFT);
      s[1] += exp2f(d[1] - SHIFT);
      s[2] += exp2f(d[2] - SHIFT);
      s[3] += exp2f(d[3] - SHIFT);
    }
    __syncthreads();
  }
  #pragma unroll
  for (int mk = 1; mk < 16; mk <<= 1)
    #pragma unroll
    for (int r = 0; r < 4; ++r) s[r] += __shfl_xor(s[r], mk);
  if (li == 0) {
    #pragma unroll
    for (int r = 0; r < 4; ++r) {
      size_t idx = (size_t)b * NN + (kt * 8 + w) * 16 + lh * 4 + r;
      cshift[idx] = SHIFT + log2f(fmaxf(s[r], 1e-30f));
    }
  }
}

// Kernel 3: out[c][i] via D[i][c] = P^T . h (PV on 32x32x16).
// Block: 4 waves (256 thr), tile i=128 x c=128, chunk k=64, grid 512
// (32 i-tiles x 2 c-halves x 8 b -> 2 blocks/CU). Wave w: iW=w&1, cW=w>>1,
// 64x64 output tile = 2x2 32x32 D-frags (2x2 operand reuse).
// S phase: wave w computes 16x16 S for ig={2w,2w+1} x kg 0..3 -> scatter one
// uint2/frag into 32x32 P^T A-frag image (dbuf 2x16KB, 1 barrier/chunk).
#define PRODUCE(DST)                                                         \
  {                                                                          \
    _Pragma("unroll")                                                        \
    for (int kg = 0; kg < 4; ++kg) {                                         \
      f32x4 s0 = __builtin_amdgcn_mfma_f32_16x16x32_bf16(afn[kg], g0, zero4, 0, 0, 0); \
      f32x4 s1 = __builtin_amdgcn_mfma_f32_16x16x32_bf16(afn[kg], g1, zero4, 0, 0, 0); \
      float4 cc = ccn[kg];                                                   \
      uint2 v0, v1;                                                          \
      v0.x = pk2(exp2f(s0[0] - cc.x), exp2f(s0[1] - cc.y));                  \
      v0.y = pk2(exp2f(s0[2] - cc.z), exp2f(s0[3] - cc.w));                  \
      v1.x = pk2(exp2f(s1[0] - cc.x), exp2f(s1[1] - cc.y));                  \
      v1.y = pk2(exp2f(s1[2] - cc.z), exp2f(s1[3] - cc.w));                  \
      char* fb = (char*)(DST) + (w * 4 + kg) * 1024 + lt16;                  \
      *(uint2*)(fb) = v0;                                                    \
      *(uint2*)(fb + 256) = v1;                                              \
    }                                                                        \
  }

__global__ __launch_bounds__(256) void k_out(
    const unsigned short* __restrict__ fA, const unsigned short* __restrict__ gB,
    const unsigned short* __restrict__ hA,
    const float* __restrict__ csv,
    const float* __restrict__ x, const float* __restrict__ gamma,
    float* __restrict__ out)
{
  __shared__ __align__(16) unsigned short pbuf[2 * 16 * 512];  // 2 x 16 KB
  const int bid = blockIdx.x;
  const int b = bid & 7, rb = bid >> 3;
  const int i0 = (rb >> 1) * 128, c0 = (rb & 1) * 128;
  const int t = threadIdx.x, w = t >> 6, l = t & 63;
  const int li = l & 15, lh = l >> 4;
  const int iW = w & 1, cW = w >> 1;
  const unsigned short* fAb = fA + (size_t)b * 256 * 512 + l * 8;
  const int cg0 = (c0 >> 5) + cW * 2;              // this wave's 2 h c-groups
  const unsigned short* hAb = hA + ((size_t)b * 8 + cg0) * (size_t)256 * 512 + l * 8;
  const float* cs = csv + (size_t)b * NN + lh * 4;
  // persistent g B-frags (16x16) for ig = 2w, 2w+1
  short8 g0 = *(const short8*)(gB + ((size_t)b * 256 + (i0 >> 4) + w * 2 + 0) * 512 + l * 8);
  short8 g1 = *(const short8*)(gB + ((size_t)b * 256 + (i0 >> 4) + w * 2 + 1) * 512 + l * 8);
  // scatter byte offset within target frag (j=0; j=1 adds 256B):
  //   value (k=kg*16+lh*4+r, i=(2w+j)*16+li) -> frag (iF=w, ks=kg),
  //   lane (lh>>1)*32 + j*16 + li, elems (lh&1)*4 .. +3  (one uint2)
  const int lt16 = (((lh >> 1) * 32 + li) * 8 + (lh & 1) * 4) * 2;
  f32x4 zero4 = {0.f, 0.f, 0.f, 0.f};
  f32x16 acc00 = {0,0,0,0,0,0,0,0,0,0,0,0,0,0,0,0};
  f32x16 acc01 = {0,0,0,0,0,0,0,0,0,0,0,0,0,0,0,0};
  f32x16 acc10 = {0,0,0,0,0,0,0,0,0,0,0,0,0,0,0,0};
  f32x16 acc11 = {0,0,0,0,0,0,0,0,0,0,0,0,0,0,0,0};
  short8 afn[4]; float4 ccn[4];
  #pragma unroll
  for (int kg = 0; kg < 4; ++kg) {
    afn[kg] = *(const short8*)(fAb + (size_t)kg * 512);
    ccn[kg] = *(const float4*)(cs + kg * 16);
  }
  PRODUCE(pbuf)                                    // P(0) -> buf0
  #pragma unroll
  for (int kg = 0; kg < 4; ++kg) {                 // operands for produce(1)
    afn[kg] = *(const short8*)(fAb + (size_t)(4 + kg) * 512);
    ccn[kg] = *(const float4*)(cs + 64 + kg * 16);
  }
  __syncthreads();
  for (int ch = 0; ch < 64; ++ch) {
    const unsigned short* pb = pbuf + (ch & 1) * 8192;
    unsigned short* pn = pbuf + ((ch + 1) & 1) * 8192;
    // issue h B-frag loads (L2 latency hides under produce)
    short8 hf[8];
    #pragma unroll
    for (int ks = 0; ks < 4; ++ks) {
      hf[ks * 2 + 0] = *(const short8*)(hAb + ((size_t)ch * 4 + ks) * 512);
      hf[ks * 2 + 1] = *(const short8*)(hAb + ((size_t)256 * 512) + ((size_t)ch * 4 + ks) * 512);
    }
    // produce P(ch+1) into the other buffer; prefetch ch+2 operands
    if (ch < 63) {
      PRODUCE(pn)
      const int ch2 = (ch < 62) ? (ch + 2) : 63;
      #pragma unroll
      for (int kg = 0; kg < 4; ++kg) {
        afn[kg] = *(const short8*)(fAb + (size_t)(ch2 * 4 + kg) * 512);
        ccn[kg] = *(const float4*)(cs + ch2 * 64 + kg * 16);
      }
    }
    // PV(ch): 16 32x32x16 MFMA, 2x2 reuse of 8 P reads + 8 h frags
    #pragma unroll
    for (int ks = 0; ks < 4; ++ks) {
      short8 pf0 = *(const short8*)(pb + (((iW * 2 + 0) * 4 + ks) * 64 + l) * 8);
      short8 pf1 = *(const short8*)(pb + (((iW * 2 + 1) * 4 + ks) * 64 + l) * 8);
      acc00 = __builtin_amdgcn_mfma_f32_32x32x16_bf16(pf0, hf[ks * 2 + 0], acc00, 0, 0, 0);
      acc01 = __builtin_amdgcn_mfma_f32_32x32x16_bf16(pf0, hf[ks * 2 + 1], acc01, 0, 0, 0);
      acc10 = __builtin_amdgcn_mfma_f32_32x32x16_bf16(pf1, hf[ks * 2 + 0], acc10, 0, 0, 0);
      acc11 = __builtin_amdgcn_mfma_f32_32x32x16_bf16(pf1, hf[ks * 2 + 1], acc11, 0, 0, 0);
    }
    __syncthreads();
  }
  // epilogue: 32x32 D: n=c=l&31, m=i=(r&3)+8*(r>>2)+4*(l>>5)
  const float gm = gamma[0];
  const int l5 = l >> 5, lm = l & 31;
  #pragma unroll
  for (int if2 = 0; if2 < 2; ++if2)
    #pragma unroll
    for (int cf = 0; cf < 2; ++cf) {
      const f32x16 accv = (if2 == 0) ? ((cf == 0) ? acc00 : acc01)
                                     : ((cf == 0) ? acc10 : acc11);
      int c = c0 + (cW * 2 + cf) * 32 + lm;
      #pragma unroll
      for (int rq = 0; rq < 4; ++rq) {
        int i = i0 + (iW * 2 + if2) * 32 + rq * 8 + l5 * 4;
        size_t off = ((size_t)b * CC + c) * NN + i;
        float4 xv = *(const float4*)(x + off);
        float4 ov;
        ov.x = gm * accv[rq * 4 + 0] + xv.x;
        ov.y = gm * accv[rq * 4 + 1] + xv.y;
        ov.z = gm * accv[rq * 4 + 2] + xv.z;
        ov.w = gm * accv[rq * 4 + 3] + xv.w;
        *(float4*)(out + off) = ov;
      }
    }
}

extern "C" void kernel_launch(void* const* d_in, const int* in_sizes, int n_in,
                              void* d_out, int out_size, void* d_ws, size_t ws_size,
                              hipStream_t stream)
{
  const float* x     = (const float*)d_in[0];
  const float* Wf    = (const float*)d_in[1];
  const float* bf    = (const float*)d_in[2];
  const float* Wg    = (const float*)d_in[3];
  const float* bg    = (const float*)d_in[4];
  const float* Wh    = (const float*)d_in[5];
  const float* bh    = (const float*)d_in[6];
  const float* gamma = (const float*)d_in[7];
  float* out = (float*)d_out;

  char* wsb = (char*)d_ws;
  float* cshift = (float*)(wsb + 131072);
  unsigned short* wA = (unsigned short*)(wsb + 262144);
  float* ball        = (float*)(wsb + 425984);
  unsigned short* fA = (unsigned short*)(wsb + 427520);
  unsigned short* gB = (unsigned short*)(wsb + 2524672);
  unsigned short* hA = (unsigned short*)(wsb + 4621824);

  k_wprep<<<40,  256, 0, stream>>>(Wf, bf, Wg, bg, Wh, bh, wA, ball);
  k_fgh  <<<512, 512, 0, stream>>>(x, wA, ball, fA, gB, hA);
  k_stats<<<256, 512, 0, stream>>>(fA, gB, cshift);
  k_out  <<<512, 256, 0, stream>>>(fA, gB, hA, cshift, x, gamma, out);
}

// Round 11
// 168.442 us; speedup vs baseline: 1.2295x; 1.2295x over previous
//
#include <hip/hip_runtime.h>
#include <hip/hip_bf16.h>

#define BB 8
#define CC 256
#define NN 4096
#define LOG2E 1.44269504088896340736f
#define SHIFT 48.0f

typedef __attribute__((ext_vector_type(8))) short short8;
typedef __attribute__((ext_vector_type(4))) float f32x4;
typedef __attribute__((ext_vector_type(16))) float f32x16;

static __device__ __forceinline__ unsigned short f2b(float x) {
  __hip_bfloat16 h = __float2bfloat16(x);   // RNE
  return *reinterpret_cast<unsigned short*>(&h);
}
static __device__ __forceinline__ unsigned int pk2(float a, float b) {
  return (unsigned int)f2b(a) | ((unsigned int)f2b(b) << 16);
}

// ---------------------------------------------------------------------------
// ws layout (bytes):
//   cshift @ 131072 : [B][N] f32  c[k] = SHIFT + log2(sum exp2(S-SHIFT))
//   wA   @ 262144   : [20 mg][8 kg][64 l][8 e] bf16 W A-frags    163840
//   ball @ 425984   : [320] f32 biases (f rows pre-scaled LOG2E)   1280
//   fA   @ 427520   : [B][256 kg][64 l][8 e] bf16 (f^T*LOG2E)   2097152
//   gB   @ 2524672  : [B][256 ig][64 l][8 e] bf16               2097152
//   hA   @ 4621824  : [B][8 cg][256 kc][64 l][8 e] bf16        16777216
//                     (32x32x16 B-frags: c=cg*32+(l&31), k=kc*16+(l>>5)*8+e)
// 16x16x32 frags: A[m][k]: lane l: m=l&15, k=(l>>4)*8+e (B same bits);
//                 D[m][n]: lane l reg r: m=(l>>4)*4+r, n=l&15
// 32x32x16 frags: A[m][k]: lane l: m=l&31, k=(l>>5)*8+e (B same bits);
//                 D[m][n]: lane l reg r: n=l&31, m=(r&3)+8*(r>>2)+4*(l>>5)
// P = exp2(S - c[k]) with c >= rowmax  ->  P in [0,1], no inf/NaN possible.
// k_out (round 11) = round-6 skeleton (best measured: 97us) with PV retyped
// to 32x32x16: same LDS/h traffic, -17% MFMA issue cycles, produce unique.
// ---------------------------------------------------------------------------

// Kernel 0: W -> A-frags (bf16), LOG2E folded into f rows; biases -> ball.
__global__ __launch_bounds__(256) void k_wprep(
    const float* __restrict__ Wf, const float* __restrict__ bfv,
    const float* __restrict__ Wg, const float* __restrict__ bgv,
    const float* __restrict__ Wh, const float* __restrict__ bhv,
    unsigned short* __restrict__ wA, float* __restrict__ ball)
{
  const int t = threadIdx.x;
  const int fi = blockIdx.x * 4 + (t >> 6);   // frag index 0..159 (mg*8+kg)
  const int l = t & 63;
  const int mg = fi >> 3, kg = fi & 7;
  const int o = mg * 16 + (l & 15);
  const int c0 = kg * 32 + (l >> 4) * 8;
  const float* src; float scale = 1.0f;
  if (o < 32)      { src = Wf + (size_t)o * CC; scale = LOG2E; }
  else if (o < 64) { src = Wg + (size_t)(o - 32) * CC; }
  else             { src = Wh + (size_t)(o - 64) * CC; }
  float4 a = *(const float4*)(src + c0);
  float4 c = *(const float4*)(src + c0 + 4);
  short8 v;
  v[0] = (short)f2b(a.x * scale); v[1] = (short)f2b(a.y * scale);
  v[2] = (short)f2b(a.z * scale); v[3] = (short)f2b(a.w * scale);
  v[4] = (short)f2b(c.x * scale); v[5] = (short)f2b(c.y * scale);
  v[6] = (short)f2b(c.z * scale); v[7] = (short)f2b(c.w * scale);
  *(short8*)(wA + (size_t)fi * 512 + l * 8) = v;
  if (blockIdx.x == 0 && t < 320)
    ball[t] = (t < 32) ? bfv[t] * LOG2E : (t < 64) ? bgv[t - 32] : bhv[t - 64];
}

// Kernel 1: fused projection GEMM (bf16 MFMA) -> frag-ready fA/gB/hA.
__global__ __launch_bounds__(512) void k_fgh(
    const float* __restrict__ x, const unsigned short* __restrict__ wA,
    const float* __restrict__ ball,
    unsigned short* __restrict__ fA, unsigned short* __restrict__ gB,
    unsigned short* __restrict__ hA)
{
  __shared__ __align__(16) char smem[41984];       // max(xb 8KB, TL 41KB)
  unsigned short* xb = (unsigned short*)smem;      // [8 frag][64 l][8 e]
  unsigned short* TL = (unsigned short*)smem;      // [64 i][328 o] bf16
  const int bid = blockIdx.x;
  const int b = bid & 7, i0 = (bid >> 3) * 64;     // batch pinned to XCD
  const int t = threadIdx.x, w = t >> 6, l = t & 63;
  const int ig_w = w & 3, mg0 = (w >> 2) * 10;
  f32x4 acc[10] = {};
  for (int cc = 0; cc < 4; ++cc) {                 // c-chunks of 64
    __syncthreads();
    {  // stage x[cc*64..+64][i0..i0+64] as 8 B-frags (bf16)
      short8 v;
      const float* xp = x + ((size_t)b * CC + cc * 64 + w * 8) * NN + i0 + l;
      #pragma unroll
      for (int e = 0; e < 8; ++e) v[e] = (short)f2b(xp[(size_t)e * NN]);
      int frag = (w >> 2) * 4 + (l >> 4);
      int lp = (w & 3) * 16 + (l & 15);
      *(short8*)(xb + (frag * 64 + lp) * 8) = v;
    }
    __syncthreads();
    #pragma unroll
    for (int kg2 = 0; kg2 < 2; ++kg2) {
      short8 bfrag = *(const short8*)(xb + ((kg2 * 4 + ig_w) * 64 + l) * 8);
      int kg = cc * 2 + kg2;
      #pragma unroll
      for (int j = 0; j < 10; ++j) {
        short8 afrag = *(const short8*)(wA +
            ((size_t)((mg0 + j) * 8 + kg)) * 512 + l * 8);
        acc[j] = __builtin_amdgcn_mfma_f32_16x16x32_bf16(afrag, bfrag, acc[j], 0, 0, 0);
      }
    }
  }
  __syncthreads();
  // D-frags (+bias) -> transpose tile TL[i][o]
  #pragma unroll
  for (int j = 0; j < 10; ++j) {
    int ob = (mg0 + j) * 16 + (l >> 4) * 4;
    float4 bl = *(const float4*)(ball + ob);
    int irow = ig_w * 16 + (l & 15);
    ushort4 pv;
    pv.x = f2b(acc[j][0] + bl.x); pv.y = f2b(acc[j][1] + bl.y);
    pv.z = f2b(acc[j][2] + bl.z); pv.w = f2b(acc[j][3] + bl.w);
    *(ushort4*)(TL + irow * 328 + ob) = pv;
  }
  __syncthreads();
  // pack fA (o 0..31, already LOG2E-scaled) and gB (o 32..63) — 16x16 frags
  if (t < 256) {
    int kg_p = t >> 6;
    int o8 = (l >> 4) * 8;
    int irow = kg_p * 16 + (l & 15);
    short8 vf = *(const short8*)(TL + irow * 328 + o8);
    short8 vg = *(const short8*)(TL + irow * 328 + 32 + o8);
    size_t kgG = (size_t)b * 256 + (i0 >> 4) + kg_p;
    *(short8*)(fA + kgG * 512 + l * 8) = vf;
    *(short8*)(gB + kgG * 512 + l * 8) = vg;
  }
  // pack hA (o 64..319) as 32x32x16 B-frags: 32 frags x 64 lanes / 2048 slots
  #pragma unroll
  for (int q = 0; q < 4; ++q) {
    int slot = t + q * 512;
    int fr = slot >> 6, ll = slot & 63;
    int cg = fr >> 2, kcl = fr & 3;
    int orow = 64 + cg * 32 + (ll & 31);
    int pbase = kcl * 16 + (ll >> 5) * 8;
    short8 v;
    #pragma unroll
    for (int e = 0; e < 8; ++e) v[e] = (short)TL[(pbase + e) * 328 + orow];
    size_t idx = (((size_t)b * 8 + cg) * 256 + (i0 >> 4) + kcl) * 512 + ll * 8;
    *(short8*)(hA + idx) = v;
  }
}

// Kernel 2: fixed-shift softmax denom, LDS-staged g tiles shared by 8 waves.
__global__ __launch_bounds__(512) void k_stats(
    const unsigned short* __restrict__ fA, const unsigned short* __restrict__ gB,
    float* __restrict__ cshift)
{
  __shared__ __align__(16) unsigned short sg[2][16 * 512];   // 2 x 16 KB
  const int bid = blockIdx.x;
  const int b = bid & 7, kt = bid >> 3;
  const int t = threadIdx.x, w = t >> 6, l = t & 63;
  const int li = l & 15, lh = l >> 4;
  short8 af = *(const short8*)(fA + ((size_t)b * 256 + kt * 8 + w) * 512 + l * 8);
  const unsigned short* gb = gB + (size_t)b * 256 * 512;
  f32x4 zero = {0.f, 0.f, 0.f, 0.f};
  {
    uint4 v0 = *(const uint4*)(gb + ((size_t)(w * 2 + 0) * 64 + l) * 8);
    uint4 v1 = *(const uint4*)(gb + ((size_t)(w * 2 + 1) * 64 + l) * 8);
    *(uint4*)(&sg[0][((w * 2 + 0) * 64 + l) * 8]) = v0;
    *(uint4*)(&sg[0][((w * 2 + 1) * 64 + l) * 8]) = v1;
  }
  __syncthreads();
  float s[4] = {0.f, 0.f, 0.f, 0.f};
  for (int jt = 0; jt < 16; ++jt) {
    if (jt < 15) {
      uint4 v0 = *(const uint4*)(gb + ((size_t)((jt + 1) * 16 + w * 2 + 0) * 64 + l) * 8);
      uint4 v1 = *(const uint4*)(gb + ((size_t)((jt + 1) * 16 + w * 2 + 1) * 64 + l) * 8);
      unsigned short* dst = &sg[(jt + 1) & 1][0];
      *(uint4*)(dst + ((w * 2 + 0) * 64 + l) * 8) = v0;
      *(uint4*)(dst + ((w * 2 + 1) * 64 + l) * 8) = v1;
    }
    const unsigned short* src = &sg[jt & 1][0];
    #pragma unroll
    for (int jf = 0; jf < 16; ++jf) {
      short8 bfrag = *(const short8*)(src + (jf * 64 + l) * 8);
      f32x4 d = __builtin_amdgcn_mfma_f32_16x16x32_bf16(af, bfrag, zero, 0, 0, 0);
      s[0] += exp2f(d[0] - SHIFT);
      s[1] += exp2f(d[1] - SHIFT);
      s[2] += exp2f(d[2] - SHIFT);
      s[3] += exp2f(d[3] - SHIFT);
    }
    __syncthreads();
  }
  #pragma unroll
  for (int mk = 1; mk < 16; mk <<= 1)
    #pragma unroll
    for (int r = 0; r < 4; ++r) s[r] += __shfl_xor(s[r], mk);
  if (li == 0) {
    #pragma unroll
    for (int r = 0; r < 4; ++r) {
      size_t idx = (size_t)b * NN + (kt * 8 + w) * 16 + lh * 4 + r;
      cshift[idx] = SHIFT + log2f(fmaxf(s[r], 1e-30f));
    }
  }
}

// Kernel 3: out[c][i] via D[i][c] = P^T . h, PV on 32x32x16.
// Round-6 skeleton: 8 waves, tile c=256 x i=64, chunk 128k, grid 512
// (2 blocks/CU, batch->XCD). Per chunk per wave: 8 h-frag loads (issued
// first), produce S kg=w (1 16x16 MFMA x 4 ig -> exp2 -> scatter one uint2
// each into 32x32 P^T A-frag image), ONE barrier, then 16 32x32 MFMAs
// (acc[2 iF] x 8 ks, wave's c-group = w). Dbuf 2x16KB prevents WAR.
__global__ __launch_bounds__(512, 4) void k_out(
    const unsigned short* __restrict__ fA, const unsigned short* __restrict__ gB,
    const unsigned short* __restrict__ hA,
    const float* __restrict__ csv,
    const float* __restrict__ x, const float* __restrict__ gamma,
    float* __restrict__ out)
{
  __shared__ __align__(16) unsigned short pbuf[2 * 16 * 512];  // 2 x 16 KB
  const int bid = blockIdx.x;
  const int b = bid & 7, i0 = (bid >> 3) * 64;     // batch pinned to XCD
  const int t = threadIdx.x, w = t >> 6, l = t & 63;
  const int li = l & 15, lh = l >> 4;
  const unsigned short* fAb = fA + ((size_t)b * 256 + w) * 512 + l * 8;
  const unsigned short* hAb = hA + ((size_t)b * 8 + w) * (size_t)256 * 512 + l * 8;
  const float* cs = csv + (size_t)b * NN + w * 16 + lh * 4;
  // persistent g B-frags (16x16) for the block's 4 ig columns
  short8 g[4];
  #pragma unroll
  for (int ig = 0; ig < 4; ++ig)
    g[ig] = *(const short8*)(gB + ((size_t)b * 256 + (i0 >> 4) + ig) * 512 + l * 8);
  // scatter: value (k=ch*128+w*16+lh*4+r, i=ig*16+li) -> frag [ig>>1][ks=w],
  //   lane (lh>>1)*32 + (ig&1)*16 + li, elems (lh&1)*4 + r (one uint2)
  const int ltb = (lh >> 1) * 32 + li;             // + (ig&1)*16 per ig
  const int eb2 = (lh & 1) * 8;                    // byte offset of elem base
  f32x4 zero = {0.f, 0.f, 0.f, 0.f};
  f32x16 acc0 = {0,0,0,0,0,0,0,0,0,0,0,0,0,0,0,0};
  f32x16 acc1 = {0,0,0,0,0,0,0,0,0,0,0,0,0,0,0,0};
  for (int ch = 0; ch < 32; ++ch) {
    // issue h B-frag loads first (L2 latency hides under produce+barrier)
    short8 hf[8];
    #pragma unroll
    for (int ks = 0; ks < 8; ++ks)
      hf[ks] = *(const short8*)(hAb + ((size_t)ch * 8 + ks) * 512);
    // produce P(ch) into buf[ch&1]
    short8 af = *(const short8*)(fAb + (size_t)ch * 8 * 512);
    float4 cc = *(const float4*)(cs + ch * 128);
    unsigned short* pb = pbuf + (ch & 1) * 8192;
    #pragma unroll
    for (int ig = 0; ig < 4; ++ig) {
      f32x4 s = __builtin_amdgcn_mfma_f32_16x16x32_bf16(af, g[ig], zero, 0, 0, 0);
      uint2 v;
      v.x = pk2(exp2f(s[0] - cc.x), exp2f(s[1] - cc.y));
      v.y = pk2(exp2f(s[2] - cc.z), exp2f(s[3] - cc.w));
      *(uint2*)((char*)pb + (((ig >> 1) * 8 + w) * 64 + ltb + (ig & 1) * 16) * 16 + eb2) = v;
    }
    __syncthreads();
    // PV(ch): 16 32x32x16 MFMAs (acc0: i 0..31, acc1: i 32..63)
    #pragma unroll
    for (int ks = 0; ks < 8; ++ks) {
      short8 pf0 = *(const short8*)(pb + ((0 * 8 + ks) * 64 + l) * 8);
      short8 pf1 = *(const short8*)(pb + ((1 * 8 + ks) * 64 + l) * 8);
      acc0 = __builtin_amdgcn_mfma_f32_32x32x16_bf16(pf0, hf[ks], acc0, 0, 0, 0);
      acc1 = __builtin_amdgcn_mfma_f32_32x32x16_bf16(pf1, hf[ks], acc1, 0, 0, 0);
    }
  }
  // epilogue: 32x32 D: c = w*32 + (l&31), i = i0 + iF*32 + rq*8 + (l>>5)*4 + r
  const float gm = gamma[0];
  const int c = w * 32 + (l & 31);
  const int l5 = (l >> 5) * 4;
  #pragma unroll
  for (int iF = 0; iF < 2; ++iF) {
    const f32x16 accv = (iF == 0) ? acc0 : acc1;
    #pragma unroll
    for (int rq = 0; rq < 4; ++rq) {
      int i = i0 + iF * 32 + rq * 8 + l5;
      size_t off = ((size_t)b * CC + c) * NN + i;
      float4 xv = *(const float4*)(x + off);
      float4 ov;
      ov.x = gm * accv[rq * 4 + 0] + xv.x;
      ov.y = gm * accv[rq * 4 + 1] + xv.y;
      ov.z = gm * accv[rq * 4 + 2] + xv.z;
      ov.w = gm * accv[rq * 4 + 3] + xv.w;
      *(float4*)(out + off) = ov;
    }
  }
}

extern "C" void kernel_launch(void* const* d_in, const int* in_sizes, int n_in,
                              void* d_out, int out_size, void* d_ws, size_t ws_size,
                              hipStream_t stream)
{
  const float* x     = (const float*)d_in[0];
  const float* Wf    = (const float*)d_in[1];
  const float* bf    = (const float*)d_in[2];
  const float* Wg    = (const float*)d_in[3];
  const float* bg    = (const float*)d_in[4];
  const float* Wh    = (const float*)d_in[5];
  const float* bh    = (const float*)d_in[6];
  const float* gamma = (const float*)d_in[7];
  float* out = (float*)d_out;

  char* wsb = (char*)d_ws;
  float* cshift = (float*)(wsb + 131072);
  unsigned short* wA = (unsigned short*)(wsb + 262144);
  float* ball        = (float*)(wsb + 425984);
  unsigned short* fA = (unsigned short*)(wsb + 427520);
  unsigned short* gB = (unsigned short*)(wsb + 2524672);
  unsigned short* hA = (unsigned short*)(wsb + 4621824);

  k_wprep<<<40,  256, 0, stream>>>(Wf, bf, Wg, bg, Wh, bh, wA, ball);
  k_fgh  <<<512, 512, 0, stream>>>(x, wA, ball, fA, gB, hA);
  k_stats<<<256, 512, 0, stream>>>(fA, gB, cshift);
  k_out  <<<512, 512, 0, stream>>>(fA, gB, hA, cshift, x, gamma, out);
}